// Round 8
// baseline (400.784 us; speedup 1.0000x reference)
//
#include <hip/hip_runtime.h>
#include <hip/hip_bf16.h>

typedef __hip_bfloat16 bf16;
typedef unsigned short ushort_t;
typedef unsigned int uint32;

typedef short short4_t __attribute__((ext_vector_type(4)));
typedef short short8_t __attribute__((ext_vector_type(8)));
typedef float float4_t __attribute__((ext_vector_type(4)));

union FragU { short4_t h[2]; short8_t v; };
union Frag16 { short8_t v; short s[8]; uint4 u; };

#define BIG 100000.0f

// ---------------------------------------------------------------------------
// prep: inst NCHW->NHWC transpose (blocks [0,2048)) + bg NCHW->NHWC
// transpose (blocks [2048,6144)) + 4x weight transform ([6144,6720)).
// All branches small-LDS/low-VGPR -> occupancy-compatible (R6 lesson).
// Alias-safe: writes instN@A, bgN@C, wt@67.6M; nothing reads C until
// conv_b1 (dispatch 5).
// Weight layout: frag-major bf16,
// wt[set][((t*4+mb)*2+half)*512 + (q*16+n)*8 + i] = w[co=mb*16+n][ci=half*32+q*8+i][t]
// ---------------------------------------------------------------------------
__global__ __launch_bounds__(256) void prep(
    const float* __restrict__ instf,  // [8][64][128][128]
    ushort_t* __restrict__ instN,     // [8][128][128][64]
    const float* __restrict__ bgf,    // [64][512][512]
    ushort_t* __restrict__ bgN,       // [512][512][64]
    const float* __restrict__ w0, const float* __restrict__ w1,
    const float* __restrict__ w2, const float* __restrict__ w3,
    ushort_t* __restrict__ wt)
{
    __shared__ ushort_t s[64 * 66];
    const int id = blockIdx.x;
    const int tid = threadIdx.x;

    if (id >= 6144) {   // ---- wtrans: 576 blocks, 4 x 36864 elements
        const int gidx = (id - 6144) * 256 + tid;        // [0,147456)
        const int set = gidx / 36864;
        const int idx = gidx - set * 36864;
        const float* w = (set == 0) ? w0 : (set == 1) ? w1 : (set == 2) ? w2 : w3;
        const int i  = idx & 7;
        const int r  = (idx >> 3) & 63;
        const int f  = idx >> 9;          // frag id [0,72)
        const int half = f & 1, mb = (f >> 1) & 3, t = f >> 3;
        const int nn = r & 15, qq = r >> 4;
        const int co = mb * 16 + nn;
        const int ci = half * 32 + qq * 8 + i;
        bf16 h = (bf16)w[(co * 64 + ci) * 9 + t];
        wt[set * 36864 + idx] = *(ushort_t*)&h;
        return;
    }

    // ---- transpose branches
    const float* in;
    ushort_t* out;
    long ibase, obase;
    int pstride;
    if (id < 2048) {        // inst: 8 imgs x 128 rows x 2 x-blocks
        const int b = id >> 8, r = id & 255;
        const int y = r >> 1, x0 = (r & 1) * 64;
        in = instf; out = instN; pstride = 16384;
        ibase = (long)b * 64 * 16384 + (long)y * 128 + x0;
        obase = ((long)b * 16384 + (long)y * 128 + x0) * 64;
    } else {                // bg: 512 rows x 8 x-blocks
        const int r = id - 2048;
        const int y = r >> 3, x0 = (r & 7) * 64;
        in = bgf; out = bgN; pstride = 262144;
        ibase = (long)y * 512 + x0;
        obase = ((long)y * 512 + x0) * 64;
    }
    {
        const int x = tid & 63, dc = tid >> 6;
        for (int c = dc; c < 64; c += 4) {
            bf16 h = (bf16)in[ibase + (long)c * pstride + x];
            s[c * 66 + x] = *(ushort_t*)&h;
        }
    }
    __syncthreads();
    {
        const int c = tid & 63, dx = tid >> 6;
        for (int x = dx; x < 64; x += 4)
            out[obase + (long)x * 64 + c] = s[c * 66 + x];
    }
}

// ---------------------------------------------------------------------------
// conv 3x3 SAME, 64->64 + bias + relu, NHWC bf16, MFMA 16x16x32.
// R4 body: 16x16 tile, single-pass staging, one barrier, frag-major weights
// direct from L2 (no weight LDS), epilogue j-outer (fully dirty lines).
// ---------------------------------------------------------------------------
__global__ __launch_bounds__(256, 2) void conv3x3_mfma(
    const ushort_t* __restrict__ in,   // [B][H][W][64] bf16
    ushort_t* __restrict__ out,        // [B][H][W][64] bf16
    const ushort_t* __restrict__ wt,   // [72][64][8] bf16 frag-major
    const float* __restrict__ bias,    // [64] f32
    int H, int W)
{
    __shared__ ushort_t s_h[2][324 * 36];   // 2 x 23,328 B = 46,656 B

    const int b = blockIdx.z;
    const int x0 = blockIdx.x * 16, y0 = blockIdx.y * 16;
    const int tid = threadIdx.x;
    const int lane = tid & 63, wv = tid >> 6;
    const int n = lane & 15, q = lane >> 4;   // n: M or N index, q: k-quad

    const long img = (long)b * H * W;

    // ---- stage input patch once: 324 px x 8 chunks(16B) = 2592
    for (int idx = tid; idx < 2592; idx += 256) {
        const int p = idx >> 3, c = idx & 7;
        const int py = p / 18, px = p - py * 18;
        const int gy = y0 - 1 + py, gx = x0 - 1 + px;
        uint4 d = {0u, 0u, 0u, 0u};
        if (gy >= 0 && gy < H && gx >= 0 && gx < W)
            d = *(const uint4*)(in + ((img + (long)gy * W + gx) << 6) + c * 8);
        ushort_t* dp = &s_h[c >> 2][p * 36 + (c & 3) * 8];
        *(uint2*)dp       = make_uint2(d.x, d.y);
        *(uint2*)(dp + 4) = make_uint2(d.z, d.w);
    }
    __syncthreads();

    float4_t acc[4][4];
#pragma unroll
    for (int mb = 0; mb < 4; ++mb)
#pragma unroll
        for (int j = 0; j < 4; ++j) acc[mb][j] = (float4_t){0.f, 0.f, 0.f, 0.f};

#pragma unroll
    for (int half = 0; half < 2; ++half) {
        const ushort_t* sh = s_h[half];
#pragma unroll
        for (int t = 0; t < 9; ++t) {
            const int dy = t / 3, dx = t - dy * 3;
            FragU A[4];
#pragma unroll
            for (int mb = 0; mb < 4; ++mb) {
                const ushort_t* ap = wt + (((t * 4 + mb) * 2 + half) << 9) + (lane << 3);
                A[mb].h[0] = *(const short4_t*)ap;
                A[mb].h[1] = *(const short4_t*)(ap + 4);
            }
#pragma unroll
            for (int j = 0; j < 4; ++j) {
                const int row = wv * 4 + j;
                const ushort_t* p = &sh[((row + dy) * 18 + n + dx) * 36 + q * 8];
                FragU B;
                B.h[0] = *(const short4_t*)p;
                B.h[1] = *(const short4_t*)(p + 4);
#pragma unroll
                for (int mb = 0; mb < 4; ++mb)
                    acc[mb][j] = __builtin_amdgcn_mfma_f32_16x16x32_bf16(
                        A[mb].v, B.v, acc[mb][j], 0, 0, 0);
            }
        }
    }

    // ---- epilogue: D[m=co][n=px]: co = mb*16 + q*4 + r, px-col = n
#pragma unroll
    for (int j = 0; j < 4; ++j) {
        const int gy = y0 + wv * 4 + j, gx = x0 + n;
        ushort_t* op0 = out + ((img + (long)gy * W + gx) << 6);
#pragma unroll
        for (int mb = 0; mb < 4; ++mb) {
            const int co = mb * 16 + q * 4;
            const float4 bv = *(const float4*)(bias + co);
            const float bvr[4] = {bv.x, bv.y, bv.z, bv.w};
            bf16 tmp[4];
#pragma unroll
            for (int r = 0; r < 4; ++r) {
                float v = acc[mb][j][r] + bvr[r];
                v = v > 0.f ? v : 0.f;
                tmp[r] = (bf16)v;
            }
            *(uint2*)(op0 + co) = *(uint2*)tmp;
        }
    }
}

// ---------------------------------------------------------------------------
// conv 3x3 SAME, 64->1 + bias + relu.  NHWC bf16 in, f32 out.
// ---------------------------------------------------------------------------
__global__ __launch_bounds__(256) void conv3x3_c1(
    const ushort_t* __restrict__ in,  // [B][H][W][64] bf16
    float* __restrict__ out,          // [B][H][W]
    const float* __restrict__ w,      // [64][9]
    const float* __restrict__ bias,   // [1]
    int H, int W)
{
    __shared__ ushort_t s_in[324 * 72];  // 46,656 B
    __shared__ float s_w[576];

    const int b = blockIdx.z;
    const int x0 = blockIdx.x * 16, y0 = blockIdx.y * 16;
    const int tid = threadIdx.x;
    for (int k = tid; k < 576; k += 256) s_w[k] = w[k];

    const long img = (long)b * H * W;
    for (int idx = tid; idx < 2592; idx += 256) {
        const int p = idx >> 3, c = idx & 7;
        const int py = p / 18, px = p - py * 18;
        const int gy = y0 - 1 + py, gx = x0 - 1 + px;
        uint4 d = {0u, 0u, 0u, 0u};
        if (gy >= 0 && gy < H && gx >= 0 && gx < W)
            d = *(const uint4*)(in + ((img + (long)gy * W + gx) << 6) + c * 8);
        *(uint4*)&s_in[p * 72 + c * 8] = d;
    }
    __syncthreads();

    const int px = tid & 15, py = tid >> 4;
    float acc = 0.f;
#pragma unroll
    for (int t = 0; t < 9; ++t) {
        const int dy = t / 3, dx = t - dy * 3;
        const ushort_t* p = &s_in[((py + dy) * 18 + px + dx) * 72];
#pragma unroll
        for (int c8 = 0; c8 < 8; ++c8) {
            Frag16 f;
            f.u = *(const uint4*)(p + c8 * 8);
#pragma unroll
            for (int i = 0; i < 8; ++i) {
                float fv = __uint_as_float(((uint32)(ushort_t)f.s[i]) << 16);
                acc += fv * s_w[(c8 * 8 + i) * 9 + t];
            }
        }
    }
    float v = acc + bias[0];
    v = v > 0.f ? v : 0.f;
    out[img + (long)(y0 + py) * W + x0 + px] = v;
}

// ---------------------------------------------------------------------------
// Fused: bilinear sample of 8 instance masks, softmax over 9 logits
// (bg +BIG outside coverage), blend CPB channels of upsampled inst + bg.
// R3 form (box-major + wave-uniform skip, scalar 4-tap gathers) with
// CPB 16->8 / z=8: VMEM-issue bound with VALU headroom -> doubled TLP
// hides gather latency; doubled softmax recompute stays under the bound.
// ---------------------------------------------------------------------------
#define CPB 8   // channels per block (64 / gridDim.z)

__global__ __launch_bounds__(256) void fuse_out(
    const float* __restrict__ inst, // [8][64][128][128]
    const float* __restrict__ bg,   // [64][512][512]
    const float* __restrict__ m,    // [8][128][128]
    const float* __restrict__ bgm,  // [512][512]
    float* __restrict__ out)        // [64][512][512]
{
    const int x = blockIdx.x * 256 + threadIdx.x;
    const int y = blockIdx.y;
    const int c0 = blockIdx.z * CPB;

    constexpr int BL[8]  = {0, 64, 128, 300, 64, 200, 32, 256};
    constexpr int BT[8]  = {0, 32, 256, 300, 128, 100, 256, 320};
    constexpr int BBW[8] = {256, 192, 320, 128, 384, 256, 160, 224};
    constexpr int BBH[8] = {256, 320, 192, 128, 256, 384, 224, 160};

    float logits[9];
    int   o00[8], oxs[8], oys[8];
    float wf00[8], wf01[8], wf10[8], wf11[8];
    bool  ins[8];
    bool any = false;

#pragma unroll
    for (int n = 0; n < 8; ++n) {
        const bool inside = (x >= BL[n]) && (x < BL[n] + BBW[n]) &&
                            (y >= BT[n]) && (y < BT[n] + BBH[n]);
        ins[n] = inside;
        float lg = 0.f;
        o00[n] = 0; oxs[n] = 0; oys[n] = 0;
        wf00[n] = wf01[n] = wf10[n] = wf11[n] = 0.f;
        if (inside) {
            any = true;
            float u = ((x - BL[n]) + 0.5f) * (128.0f / BBW[n]) - 0.5f;
            float v = ((y - BT[n]) + 0.5f) * (128.0f / BBH[n]) - 0.5f;
            u = fminf(fmaxf(u, 0.f), 127.f);
            v = fminf(fmaxf(v, 0.f), 127.f);
            int   xx0 = (int)u;  float fx = u - (float)xx0;
            int   yy0 = (int)v;  float fy = v - (float)yy0;
            o00[n] = yy0 * 128 + xx0;
            oxs[n] = (xx0 < 127) ? 1 : 0;
            oys[n] = (yy0 < 127) ? 128 : 0;
            wf00[n] = (1.f - fx) * (1.f - fy);
            wf01[n] = fx * (1.f - fy);
            wf10[n] = (1.f - fx) * fy;
            wf11[n] = fx * fy;
            const float* mp = m + n * 16384;
            lg = wf00[n] * mp[o00[n]] + wf01[n] * mp[o00[n] + oxs[n]] +
                 wf10[n] * mp[o00[n] + oys[n]] +
                 wf11[n] * mp[o00[n] + oxs[n] + oys[n]];
        }
        logits[n] = lg;
    }
    logits[8] = bgm[y * 512 + x] + (any ? 0.f : BIG);

    float mx = logits[0];
#pragma unroll
    for (int i = 1; i < 9; ++i) mx = fmaxf(mx, logits[i]);
    float wgt[9], s = 0.f;
#pragma unroll
    for (int i = 0; i < 9; ++i) { wgt[i] = __expf(logits[i] - mx); s += wgt[i]; }
    const float inv = 1.f / s;
#pragma unroll
    for (int i = 0; i < 9; ++i) wgt[i] *= inv;

#pragma unroll
    for (int n = 0; n < 8; ++n) {
        wf00[n] *= wgt[n]; wf01[n] *= wgt[n];
        wf10[n] *= wgt[n]; wf11[n] *= wgt[n];
    }

    const long pix = (long)y * 512 + x;

    // ---- bg term first (same summation order as before)
    const float* bgp = bg + (long)c0 * 262144 + pix;
    float o[CPB];
#pragma unroll
    for (int cc = 0; cc < CPB; ++cc)
        o[cc] = wgt[8] * bgp[(long)cc * 262144];

    // ---- box-major gather+accumulate, wave-uniform skip per box
#pragma unroll
    for (int n = 0; n < 8; ++n) {
        if (__any((int)ins[n])) {
            const int   ox  = oxs[n], oy = oys[n], oxy = oxs[n] + oys[n];
            const float w00 = wf00[n], w01 = wf01[n];
            const float w10 = wf10[n], w11 = wf11[n];
            const float* p = inst + (long)(n * 64 + c0) * 16384 + o00[n];
#pragma unroll
            for (int cc = 0; cc < CPB; ++cc) {
                o[cc] += w00 * p[0]  + w01 * p[ox] +
                         w10 * p[oy] + w11 * p[oxy];
                p += 16384;
            }
        }
    }

    float* outp = out + (long)c0 * 262144 + pix;
#pragma unroll
    for (int cc = 0; cc < CPB; ++cc)
        __builtin_nontemporal_store(o[cc], outp + (long)cc * 262144);
}

// ---------------------------------------------------------------------------
extern "C" void kernel_launch(void* const* d_in, const int* in_sizes, int n_in,
                              void* d_out, int out_size, void* d_ws, size_t ws_size,
                              hipStream_t stream)
{
    (void)in_sizes; (void)n_in; (void)out_size; (void)ws_size;

    const float* instf = (const float*)d_in[0];   // 8x64x128x128
    const float* bgf   = (const float*)d_in[1];   // 1x64x512x512
    const float* iw1   = (const float*)d_in[2];
    const float* ib1   = (const float*)d_in[3];
    const float* iw2   = (const float*)d_in[4];
    const float* ib2   = (const float*)d_in[5];
    const float* iw3   = (const float*)d_in[6];
    const float* ib3   = (const float*)d_in[7];
    const float* bw1   = (const float*)d_in[8];
    const float* bb1   = (const float*)d_in[9];
    const float* bw2   = (const float*)d_in[10];
    const float* bb2   = (const float*)d_in[11];
    const float* bw3   = (const float*)d_in[12];
    const float* bb3   = (const float*)d_in[13];

    // workspace layout (68,681,728 B), regions A=[0,16.78M) B=[16.78,33.55M)
    // C=[33.55,67.1M):
    //   instN@A -> y1@B -> y2@A ; bgN@C (prep) -> bg1@A+B -> bg2@C
    //   minst f32 @67,108,864 (0.5M)
    //   bgmask f32 @67,633,152 (1M)  [wt bf16 aliased: dead after convB2]
    // Serial order makes every write land on dead data only.
    char* ws = (char*)d_ws;
    ushort_t* instN = (ushort_t*)(ws);
    ushort_t* y1    = (ushort_t*)(ws + 16777216);
    ushort_t* y2    = (ushort_t*)(ws);
    ushort_t* bgN   = (ushort_t*)(ws + 33554432);
    ushort_t* bg1   = (ushort_t*)(ws);
    ushort_t* bg2   = (ushort_t*)(ws + 33554432);
    float*    minst  = (float*)(ws + 67108864);
    float*    bgmask = (float*)(ws + 67633152);
    ushort_t* wt0 = (ushort_t*)(ws + 67633152);         // aliased w/ bgmask
    ushort_t* wt1 = wt0 + 36864;
    ushort_t* wt2 = wt0 + 2 * 36864;
    ushort_t* wt3 = wt0 + 3 * 36864;

    // 8 dispatches
    // D1: inst transpose + bg transpose + all 4 weight transforms
    //     (all small-LDS/low-VGPR: occupancy-compatible merge)
    prep<<<6720, 256, 0, stream>>>(instf, instN, bgf, bgN,
                                   iw1, iw2, bw1, bw2, wt0);
    // D2-D4: inst convs + c1
    conv3x3_mfma<<<dim3(8, 8, 8), 256, 0, stream>>>(instN, y1, wt0, ib1, 128, 128);
    conv3x3_mfma<<<dim3(8, 8, 8), 256, 0, stream>>>(y1, y2, wt1, ib2, 128, 128);
    conv3x3_c1  <<<dim3(8, 8, 8), 256, 0, stream>>>(y2, minst, iw3, ib3, 128, 128);
    // D5-D7: bg convs + c1
    conv3x3_mfma<<<dim3(32, 32, 1), 256, 0, stream>>>(bgN, bg1, wt2, bb1, 512, 512);
    conv3x3_mfma<<<dim3(32, 32, 1), 256, 0, stream>>>(bg1, bg2, wt3, bb2, 512, 512);
    conv3x3_c1  <<<dim3(32, 32, 1), 256, 0, stream>>>(bg2, bgmask, bw3, bb3, 512, 512);
    // D8: fused resize + softmax + blend  (z = 8 channel slices of 8)
    fuse_out<<<dim3(2, 512, 8), 256, 0, stream>>>(instf, bgf, minst, bgmask, (float*)d_out);
}

// Round 9
// 373.682 us; speedup vs baseline: 1.0725x; 1.0725x over previous
//
#include <hip/hip_runtime.h>
#include <hip/hip_bf16.h>

typedef __hip_bfloat16 bf16;
typedef unsigned short ushort_t;
typedef unsigned int uint32;

typedef short short4_t __attribute__((ext_vector_type(4)));
typedef short short8_t __attribute__((ext_vector_type(8)));
typedef float float4_t __attribute__((ext_vector_type(4)));

union FragU { short4_t h[2]; short8_t v; };
union Frag16 { short8_t v; short s[8]; uint4 u; };

#define BIG 100000.0f

// ---------------------------------------------------------------------------
// prep: inst NCHW->NHWC transpose (blocks [0,2048)) + bg NCHW->NHWC
// transpose ([2048,6144)) + 4x weight transform ([6144,6720)).
// v2 transposes: VECTORIZED.  Phase 1: float4 loads (16B/lane), pack 4 bf16
// as 2x uint into LDS (4B-aligned; 2-way bank aliasing = free).  Phase 2:
// gather 4 LDS rows, store uint2 (8B/lane, 512B/wave contiguous).
// Same per-element (bf16) cast -> bitwise-identical output.
// Weight layout: frag-major bf16,
// wt[set][((t*4+mb)*2+half)*512 + (q*16+n)*8 + i] = w[co=mb*16+n][ci=half*32+q*8+i][t]
// ---------------------------------------------------------------------------
__global__ __launch_bounds__(256) void prep(
    const float* __restrict__ instf,  // [8][64][128][128]
    ushort_t* __restrict__ instN,     // [8][128][128][64]
    const float* __restrict__ bgf,    // [64][512][512]
    ushort_t* __restrict__ bgN,       // [512][512][64]
    const float* __restrict__ w0, const float* __restrict__ w1,
    const float* __restrict__ w2, const float* __restrict__ w3,
    ushort_t* __restrict__ wt)
{
    __shared__ ushort_t s[64 * 66];
    const int id = blockIdx.x;
    const int tid = threadIdx.x;

    if (id >= 6144) {   // ---- wtrans: 576 blocks, 4 x 36864 elements
        const int gidx = (id - 6144) * 256 + tid;        // [0,147456)
        const int set = gidx / 36864;
        const int idx = gidx - set * 36864;
        const float* w = (set == 0) ? w0 : (set == 1) ? w1 : (set == 2) ? w2 : w3;
        const int i  = idx & 7;
        const int r  = (idx >> 3) & 63;
        const int f  = idx >> 9;          // frag id [0,72)
        const int half = f & 1, mb = (f >> 1) & 3, t = f >> 3;
        const int nn = r & 15, qq = r >> 4;
        const int co = mb * 16 + nn;
        const int ci = half * 32 + qq * 8 + i;
        bf16 h = (bf16)w[(co * 64 + ci) * 9 + t];
        wt[set * 36864 + idx] = *(ushort_t*)&h;
        return;
    }

    // ---- transpose branches
    const float* in;
    ushort_t* out;
    long ibase, obase;
    int pstride;
    if (id < 2048) {        // inst: 8 imgs x 128 rows x 2 x-blocks
        const int b = id >> 8, r = id & 255;
        const int y = r >> 1, x0 = (r & 1) * 64;
        in = instf; out = instN; pstride = 16384;
        ibase = (long)b * 64 * 16384 + (long)y * 128 + x0;
        obase = ((long)b * 16384 + (long)y * 128 + x0) * 64;
    } else {                // bg: 512 rows x 8 x-blocks
        const int r = id - 2048;
        const int y = r >> 3, x0 = (r & 7) * 64;
        in = bgf; out = bgN; pstride = 262144;
        ibase = (long)y * 512 + x0;
        obase = ((long)y * 512 + x0) * 64;
    }

    const int k = tid & 15, cg = tid >> 4;   // k: x/c quad index, cg: row group
    // ---- phase 1: float4 loads, bf16 pack, LDS store as 2x uint
#pragma unroll
    for (int p = 0; p < 4; ++p) {
        const int c = p * 16 + cg;
        const int xq = k * 4;
        const float4 v = *(const float4*)(in + ibase + (long)c * pstride + xq);
        bf16 h0 = (bf16)v.x, h1 = (bf16)v.y, h2 = (bf16)v.z, h3 = (bf16)v.w;
        const uint32 lo = (uint32)(*(ushort_t*)&h0) | ((uint32)(*(ushort_t*)&h1) << 16);
        const uint32 hi = (uint32)(*(ushort_t*)&h2) | ((uint32)(*(ushort_t*)&h3) << 16);
        uint32* sp = (uint32*)&s[c * 66 + xq];
        sp[0] = lo; sp[1] = hi;
    }
    __syncthreads();
    // ---- phase 2: gather 4 LDS rows (stride 66, 2-way bank alias = free),
    //      store uint2 (8B/lane; 16 lanes cover one x's 128B c-line)
#pragma unroll
    for (int p = 0; p < 4; ++p) {
        const int x = p * 16 + cg;
        const int cq = k * 4;
        const uint32 lo = (uint32)s[cq * 66 + x] | ((uint32)s[(cq + 1) * 66 + x] << 16);
        const uint32 hi = (uint32)s[(cq + 2) * 66 + x] | ((uint32)s[(cq + 3) * 66 + x] << 16);
        *(uint2*)(out + obase + (long)x * 64 + cq) = make_uint2(lo, hi);
    }
}

// ---------------------------------------------------------------------------
// conv 3x3 SAME, 64->64 + bias + relu, NHWC bf16, MFMA 16x16x32.
// R4 body: 16x16 tile, single-pass staging, one barrier, frag-major weights
// direct from L2 (no weight LDS), epilogue j-outer (fully dirty lines).
// ---------------------------------------------------------------------------
__global__ __launch_bounds__(256, 2) void conv3x3_mfma(
    const ushort_t* __restrict__ in,   // [B][H][W][64] bf16
    ushort_t* __restrict__ out,        // [B][H][W][64] bf16
    const ushort_t* __restrict__ wt,   // [72][64][8] bf16 frag-major
    const float* __restrict__ bias,    // [64] f32
    int H, int W)
{
    __shared__ ushort_t s_h[2][324 * 36];   // 2 x 23,328 B = 46,656 B

    const int b = blockIdx.z;
    const int x0 = blockIdx.x * 16, y0 = blockIdx.y * 16;
    const int tid = threadIdx.x;
    const int lane = tid & 63, wv = tid >> 6;
    const int n = lane & 15, q = lane >> 4;   // n: M or N index, q: k-quad

    const long img = (long)b * H * W;

    // ---- stage input patch once: 324 px x 8 chunks(16B) = 2592
    for (int idx = tid; idx < 2592; idx += 256) {
        const int p = idx >> 3, c = idx & 7;
        const int py = p / 18, px = p - py * 18;
        const int gy = y0 - 1 + py, gx = x0 - 1 + px;
        uint4 d = {0u, 0u, 0u, 0u};
        if (gy >= 0 && gy < H && gx >= 0 && gx < W)
            d = *(const uint4*)(in + ((img + (long)gy * W + gx) << 6) + c * 8);
        ushort_t* dp = &s_h[c >> 2][p * 36 + (c & 3) * 8];
        *(uint2*)dp       = make_uint2(d.x, d.y);
        *(uint2*)(dp + 4) = make_uint2(d.z, d.w);
    }
    __syncthreads();

    float4_t acc[4][4];
#pragma unroll
    for (int mb = 0; mb < 4; ++mb)
#pragma unroll
        for (int j = 0; j < 4; ++j) acc[mb][j] = (float4_t){0.f, 0.f, 0.f, 0.f};

#pragma unroll
    for (int half = 0; half < 2; ++half) {
        const ushort_t* sh = s_h[half];
#pragma unroll
        for (int t = 0; t < 9; ++t) {
            const int dy = t / 3, dx = t - dy * 3;
            FragU A[4];
#pragma unroll
            for (int mb = 0; mb < 4; ++mb) {
                const ushort_t* ap = wt + (((t * 4 + mb) * 2 + half) << 9) + (lane << 3);
                A[mb].h[0] = *(const short4_t*)ap;
                A[mb].h[1] = *(const short4_t*)(ap + 4);
            }
#pragma unroll
            for (int j = 0; j < 4; ++j) {
                const int row = wv * 4 + j;
                const ushort_t* p = &sh[((row + dy) * 18 + n + dx) * 36 + q * 8];
                FragU B;
                B.h[0] = *(const short4_t*)p;
                B.h[1] = *(const short4_t*)(p + 4);
#pragma unroll
                for (int mb = 0; mb < 4; ++mb)
                    acc[mb][j] = __builtin_amdgcn_mfma_f32_16x16x32_bf16(
                        A[mb].v, B.v, acc[mb][j], 0, 0, 0);
            }
        }
    }

    // ---- epilogue: D[m=co][n=px]: co = mb*16 + q*4 + r, px-col = n
#pragma unroll
    for (int j = 0; j < 4; ++j) {
        const int gy = y0 + wv * 4 + j, gx = x0 + n;
        ushort_t* op0 = out + ((img + (long)gy * W + gx) << 6);
#pragma unroll
        for (int mb = 0; mb < 4; ++mb) {
            const int co = mb * 16 + q * 4;
            const float4 bv = *(const float4*)(bias + co);
            const float bvr[4] = {bv.x, bv.y, bv.z, bv.w};
            bf16 tmp[4];
#pragma unroll
            for (int r = 0; r < 4; ++r) {
                float v = acc[mb][j][r] + bvr[r];
                v = v > 0.f ? v : 0.f;
                tmp[r] = (bf16)v;
            }
            *(uint2*)(op0 + co) = *(uint2*)tmp;
        }
    }
}

// ---------------------------------------------------------------------------
// conv 3x3 SAME, 64->1 + bias + relu.  NHWC bf16 in, f32 out.
// ---------------------------------------------------------------------------
__global__ __launch_bounds__(256) void conv3x3_c1(
    const ushort_t* __restrict__ in,  // [B][H][W][64] bf16
    float* __restrict__ out,          // [B][H][W]
    const float* __restrict__ w,      // [64][9]
    const float* __restrict__ bias,   // [1]
    int H, int W)
{
    __shared__ ushort_t s_in[324 * 72];  // 46,656 B
    __shared__ float s_w[576];

    const int b = blockIdx.z;
    const int x0 = blockIdx.x * 16, y0 = blockIdx.y * 16;
    const int tid = threadIdx.x;
    for (int k = tid; k < 576; k += 256) s_w[k] = w[k];

    const long img = (long)b * H * W;
    for (int idx = tid; idx < 2592; idx += 256) {
        const int p = idx >> 3, c = idx & 7;
        const int py = p / 18, px = p - py * 18;
        const int gy = y0 - 1 + py, gx = x0 - 1 + px;
        uint4 d = {0u, 0u, 0u, 0u};
        if (gy >= 0 && gy < H && gx >= 0 && gx < W)
            d = *(const uint4*)(in + ((img + (long)gy * W + gx) << 6) + c * 8);
        *(uint4*)&s_in[p * 72 + c * 8] = d;
    }
    __syncthreads();

    const int px = tid & 15, py = tid >> 4;
    float acc = 0.f;
#pragma unroll
    for (int t = 0; t < 9; ++t) {
        const int dy = t / 3, dx = t - dy * 3;
        const ushort_t* p = &s_in[((py + dy) * 18 + px + dx) * 72];
#pragma unroll
        for (int c8 = 0; c8 < 8; ++c8) {
            Frag16 f;
            f.u = *(const uint4*)(p + c8 * 8);
#pragma unroll
            for (int i = 0; i < 8; ++i) {
                float fv = __uint_as_float(((uint32)(ushort_t)f.s[i]) << 16);
                acc += fv * s_w[(c8 * 8 + i) * 9 + t];
            }
        }
    }
    float v = acc + bias[0];
    v = v > 0.f ? v : 0.f;
    out[img + (long)(y0 + py) * W + x0 + px] = v;
}

// ---------------------------------------------------------------------------
// Fused: bilinear sample of 8 instance masks, softmax over 9 logits
// (bg +BIG outside coverage), blend CPB channels of upsampled inst + bg.
// R3/R7 form: box-major + wave-uniform skip, scalar 4-tap gathers, CPB=16
// (CPB=8 regressed: doubled per-pixel softmax/setup was not free).
// ---------------------------------------------------------------------------
#define CPB 16   // channels per block (64 / gridDim.z)

__global__ __launch_bounds__(256) void fuse_out(
    const float* __restrict__ inst, // [8][64][128][128]
    const float* __restrict__ bg,   // [64][512][512]
    const float* __restrict__ m,    // [8][128][128]
    const float* __restrict__ bgm,  // [512][512]
    float* __restrict__ out)        // [64][512][512]
{
    const int x = blockIdx.x * 256 + threadIdx.x;
    const int y = blockIdx.y;
    const int c0 = blockIdx.z * CPB;

    constexpr int BL[8]  = {0, 64, 128, 300, 64, 200, 32, 256};
    constexpr int BT[8]  = {0, 32, 256, 300, 128, 100, 256, 320};
    constexpr int BBW[8] = {256, 192, 320, 128, 384, 256, 160, 224};
    constexpr int BBH[8] = {256, 320, 192, 128, 256, 384, 224, 160};

    float logits[9];
    int   o00[8], oxs[8], oys[8];
    float wf00[8], wf01[8], wf10[8], wf11[8];
    bool  ins[8];
    bool any = false;

#pragma unroll
    for (int n = 0; n < 8; ++n) {
        const bool inside = (x >= BL[n]) && (x < BL[n] + BBW[n]) &&
                            (y >= BT[n]) && (y < BT[n] + BBH[n]);
        ins[n] = inside;
        float lg = 0.f;
        o00[n] = 0; oxs[n] = 0; oys[n] = 0;
        wf00[n] = wf01[n] = wf10[n] = wf11[n] = 0.f;
        if (inside) {
            any = true;
            float u = ((x - BL[n]) + 0.5f) * (128.0f / BBW[n]) - 0.5f;
            float v = ((y - BT[n]) + 0.5f) * (128.0f / BBH[n]) - 0.5f;
            u = fminf(fmaxf(u, 0.f), 127.f);
            v = fminf(fmaxf(v, 0.f), 127.f);
            int   xx0 = (int)u;  float fx = u - (float)xx0;
            int   yy0 = (int)v;  float fy = v - (float)yy0;
            o00[n] = yy0 * 128 + xx0;
            oxs[n] = (xx0 < 127) ? 1 : 0;
            oys[n] = (yy0 < 127) ? 128 : 0;
            wf00[n] = (1.f - fx) * (1.f - fy);
            wf01[n] = fx * (1.f - fy);
            wf10[n] = (1.f - fx) * fy;
            wf11[n] = fx * fy;
            const float* mp = m + n * 16384;
            lg = wf00[n] * mp[o00[n]] + wf01[n] * mp[o00[n] + oxs[n]] +
                 wf10[n] * mp[o00[n] + oys[n]] +
                 wf11[n] * mp[o00[n] + oxs[n] + oys[n]];
        }
        logits[n] = lg;
    }
    logits[8] = bgm[y * 512 + x] + (any ? 0.f : BIG);

    float mx = logits[0];
#pragma unroll
    for (int i = 1; i < 9; ++i) mx = fmaxf(mx, logits[i]);
    float wgt[9], s = 0.f;
#pragma unroll
    for (int i = 0; i < 9; ++i) { wgt[i] = __expf(logits[i] - mx); s += wgt[i]; }
    const float inv = 1.f / s;
#pragma unroll
    for (int i = 0; i < 9; ++i) wgt[i] *= inv;

#pragma unroll
    for (int n = 0; n < 8; ++n) {
        wf00[n] *= wgt[n]; wf01[n] *= wgt[n];
        wf10[n] *= wgt[n]; wf11[n] *= wgt[n];
    }

    const long pix = (long)y * 512 + x;

    // ---- bg term first (same summation order as before)
    const float* bgp = bg + (long)c0 * 262144 + pix;
    float o[CPB];
#pragma unroll
    for (int cc = 0; cc < CPB; ++cc)
        o[cc] = wgt[8] * bgp[(long)cc * 262144];

    // ---- box-major gather+accumulate, wave-uniform skip per box
#pragma unroll
    for (int n = 0; n < 8; ++n) {
        if (__any((int)ins[n])) {
            const int   ox  = oxs[n], oy = oys[n], oxy = oxs[n] + oys[n];
            const float w00 = wf00[n], w01 = wf01[n];
            const float w10 = wf10[n], w11 = wf11[n];
            const float* p = inst + (long)(n * 64 + c0) * 16384 + o00[n];
#pragma unroll
            for (int cc = 0; cc < CPB; ++cc) {
                o[cc] += w00 * p[0]  + w01 * p[ox] +
                         w10 * p[oy] + w11 * p[oxy];
                p += 16384;
            }
        }
    }

    float* outp = out + (long)c0 * 262144 + pix;
#pragma unroll
    for (int cc = 0; cc < CPB; ++cc)
        __builtin_nontemporal_store(o[cc], outp + (long)cc * 262144);
}

// ---------------------------------------------------------------------------
extern "C" void kernel_launch(void* const* d_in, const int* in_sizes, int n_in,
                              void* d_out, int out_size, void* d_ws, size_t ws_size,
                              hipStream_t stream)
{
    (void)in_sizes; (void)n_in; (void)out_size; (void)ws_size;

    const float* instf = (const float*)d_in[0];   // 8x64x128x128
    const float* bgf   = (const float*)d_in[1];   // 1x64x512x512
    const float* iw1   = (const float*)d_in[2];
    const float* ib1   = (const float*)d_in[3];
    const float* iw2   = (const float*)d_in[4];
    const float* ib2   = (const float*)d_in[5];
    const float* iw3   = (const float*)d_in[6];
    const float* ib3   = (const float*)d_in[7];
    const float* bw1   = (const float*)d_in[8];
    const float* bb1   = (const float*)d_in[9];
    const float* bw2   = (const float*)d_in[10];
    const float* bb2   = (const float*)d_in[11];
    const float* bw3   = (const float*)d_in[12];
    const float* bb3   = (const float*)d_in[13];

    // workspace layout (68,681,728 B), regions A=[0,16.78M) B=[16.78,33.55M)
    // C=[33.55,67.1M):
    //   instN@A -> y1@B -> y2@A ; bgN@C (prep) -> bg1@A+B -> bg2@C
    //   minst f32 @67,108,864 (0.5M)
    //   bgmask f32 @67,633,152 (1M)  [wt bf16 aliased: dead after convB2]
    // Serial order makes every write land on dead data only.
    char* ws = (char*)d_ws;
    ushort_t* instN = (ushort_t*)(ws);
    ushort_t* y1    = (ushort_t*)(ws + 16777216);
    ushort_t* y2    = (ushort_t*)(ws);
    ushort_t* bgN   = (ushort_t*)(ws + 33554432);
    ushort_t* bg1   = (ushort_t*)(ws);
    ushort_t* bg2   = (ushort_t*)(ws + 33554432);
    float*    minst  = (float*)(ws + 67108864);
    float*    bgmask = (float*)(ws + 67633152);
    ushort_t* wt0 = (ushort_t*)(ws + 67633152);         // aliased w/ bgmask
    ushort_t* wt1 = wt0 + 36864;
    ushort_t* wt2 = wt0 + 2 * 36864;
    ushort_t* wt3 = wt0 + 3 * 36864;

    // 8 dispatches
    // D1: inst transpose + bg transpose + all 4 weight transforms
    //     (all small-LDS/low-VGPR: occupancy-compatible merge; vectorized)
    prep<<<6720, 256, 0, stream>>>(instf, instN, bgf, bgN,
                                   iw1, iw2, bw1, bw2, wt0);
    // D2-D4: inst convs + c1
    conv3x3_mfma<<<dim3(8, 8, 8), 256, 0, stream>>>(instN, y1, wt0, ib1, 128, 128);
    conv3x3_mfma<<<dim3(8, 8, 8), 256, 0, stream>>>(y1, y2, wt1, ib2, 128, 128);
    conv3x3_c1  <<<dim3(8, 8, 8), 256, 0, stream>>>(y2, minst, iw3, ib3, 128, 128);
    // D5-D7: bg convs + c1
    conv3x3_mfma<<<dim3(32, 32, 1), 256, 0, stream>>>(bgN, bg1, wt2, bb1, 512, 512);
    conv3x3_mfma<<<dim3(32, 32, 1), 256, 0, stream>>>(bg1, bg2, wt3, bb2, 512, 512);
    conv3x3_c1  <<<dim3(32, 32, 1), 256, 0, stream>>>(bg2, bgmask, bw3, bb3, 512, 512);
    // D8: fused resize + softmax + blend  (z = 4 channel slices of 16)
    fuse_out<<<dim3(2, 512, 4), 256, 0, stream>>>(instf, bgf, minst, bgmask, (float*)d_out);
}